// Round 9
// baseline (356.766 us; speedup 1.0000x reference)
//
#include <hip/hip_runtime.h>
#include <hip/hip_bf16.h>

typedef __attribute__((ext_vector_type(8))) __bf16 bf16x8;
typedef __attribute__((ext_vector_type(4))) short short4v;
typedef __attribute__((ext_vector_type(4))) float f32x4;
typedef __attribute__((ext_vector_type(4))) unsigned int uint4v;
typedef __attribute__((ext_vector_type(2))) unsigned int uint2v;

#define S_LEN 2048
#define DIM_  1024
#define HDIM  64
// SCALE * log2(e), folded into Q at projection time
#define SCALE2 0.045084441f
#define QK_STR 80    // Qs/Ks row stride (160 B) — round-7 measured-best
#define VT_STR 136   // Vt row stride for 128-kv tile (272 B, 16B multiple)

#define EXP2F(x) __builtin_amdgcn_exp2f(x)

__device__ __forceinline__ void async_copy16(const void* gp, void* lp) {
  __builtin_amdgcn_global_load_lds(
      (const __attribute__((address_space(1))) unsigned int*)gp,
      (__attribute__((address_space(3))) unsigned int*)lp, 16, 0, 0);
}

__device__ __forceinline__ unsigned f2bf_u(float f) {
  unsigned u = __builtin_bit_cast(unsigned, f);
  return (u + 0x7FFFu + ((u >> 16) & 1u)) >> 16;
}
__device__ __forceinline__ unsigned pack2(float a, float b) {
  return f2bf_u(a) | (f2bf_u(b) << 16);
}
// round-half-up bf16 pair pack: 2 adds + 1 v_perm
__device__ __forceinline__ unsigned pack2f(float a, float b) {
  unsigned ua = __builtin_bit_cast(unsigned, a) + 0x8000u;
  unsigned ub = __builtin_bit_cast(unsigned, b) + 0x8000u;
  return __builtin_amdgcn_perm(ub, ua, 0x07060302u);
}

// ---------------- input f32 -> bf16 conversion ----------------
__global__ __launch_bounds__(256) void cvt_kernel(
    const float* __restrict__ s0, const float* __restrict__ s1, const float* __restrict__ s2,
    const float* __restrict__ s3, const float* __restrict__ s4, const float* __restrict__ s5,
    const float* __restrict__ s6,
    __hip_bfloat16* __restrict__ d0, __hip_bfloat16* __restrict__ d1, __hip_bfloat16* __restrict__ d2,
    __hip_bfloat16* __restrict__ d3, __hip_bfloat16* __restrict__ d4, __hip_bfloat16* __restrict__ d5,
    __hip_bfloat16* __restrict__ d6)
{
  const float* srcs[7] = {s0, s1, s2, s3, s4, s5, s6};
  __hip_bfloat16* dsts[7] = {d0, d1, d2, d3, d4, d5, d6};
  const int sizes[7] = {4194304, 4194304, 4194304, 1048576, 1048576, 1048576, 1048576};
  int rg = blockIdx.y;
  int base = (blockIdx.x * 256 + threadIdx.x) * 8;
  if (base >= sizes[rg]) return;
  const float* s = srcs[rg] + base;
  f32x4 a = *(const f32x4*)s;
  f32x4 b = *(const f32x4*)(s + 4);
  uint4v o;
  o.x = pack2(a[0], a[1]); o.y = pack2(a[2], a[3]);
  o.z = pack2(b[0], b[1]); o.w = pack2(b[2], b[3]);
  *(uint4v*)(dsts[rg] + base) = o;
}

// ---------------- mask int32 -> 64-bit words via ballot ----------------
__global__ __launch_bounds__(256) void maskbits_kernel(
    const int* __restrict__ mask, unsigned long long* __restrict__ bits)
{
  int w = (blockIdx.x * 256 + threadIdx.x) >> 6;
  int lane = threadIdx.x & 63;
  int m = mask[(size_t)w * 64 + lane];
  unsigned long long bal = __ballot(m != 0);
  if (lane == 0) bits[w] = bal;
}

// L2 swizzle: 8 consecutive blocks share one n-tile, sweep m
__device__ __forceinline__ void swz(int r, int& m0, int& n0) {
  int g  = r >> 6;
  int yy = (r >> 3) & 7;
  int xl = r & 7;
  m0 = (g * 8 + xl) * 128;
  n0 = yy * 128;
}

// ---------------- QKV projection (bf16, async staging) ----------------
__global__ __launch_bounds__(256) void qkv_gemm_kernel(
    const __hip_bfloat16* __restrict__ xq, const __hip_bfloat16* __restrict__ xk,
    const __hip_bfloat16* __restrict__ xv,
    const __hip_bfloat16* __restrict__ Wq, const float* __restrict__ bq,
    const __hip_bfloat16* __restrict__ Wk, const float* __restrict__ bk,
    const __hip_bfloat16* __restrict__ Wv, const float* __restrict__ bv,
    __hip_bfloat16* __restrict__ Q, __hip_bfloat16* __restrict__ Kk,
    __hip_bfloat16* __restrict__ VT)
{
  const __hip_bfloat16 *X, *W; const float* bias;
  if (blockIdx.z == 0)      { X = xq; W = Wq; bias = bq; }
  else if (blockIdx.z == 1) { X = xk; W = Wk; bias = bk; }
  else                      { X = xv; W = Wv; bias = bv; }

  constexpr int K = 1024, N = 1024;
  __shared__ alignas(16) __hip_bfloat16 As[128 * 32];
  __shared__ alignas(16) __hip_bfloat16 Bs[128 * 32];
  const int tid  = threadIdx.x;
  const int lane = tid & 63;
  const int wave = tid >> 6;
  const int t    = lane & 15;
  const int quad = lane >> 4;
  const int wm   = wave >> 1;
  const int wn   = wave & 1;
  int m0, n0;
  swz(blockIdx.x, m0, n0);

  f32x4 acc[4][4] = {};

  for (int k0 = 0; k0 < K; k0 += 32) {
    __syncthreads();
#pragma unroll
    for (int r = 0; r < 2; ++r) {
      int c   = r * 256 + tid;
      int row = c >> 2;
      int col = (c & 3) * 8;
      async_copy16(&X[(size_t)(m0 + row) * K + k0 + col], &As[c * 8]);
      async_copy16(&W[(size_t)(n0 + row) * K + k0 + col], &Bs[c * 8]);
    }
    __syncthreads();
    bf16x8 a[4], b[4];
#pragma unroll
    for (int i = 0; i < 4; ++i)
      a[i] = *(const bf16x8*)&As[(wm * 64 + i * 16 + t) * 32 + quad * 8];
#pragma unroll
    for (int j = 0; j < 4; ++j)
      b[j] = *(const bf16x8*)&Bs[(wn * 64 + j * 16 + t) * 32 + quad * 8];
#pragma unroll
    for (int i = 0; i < 4; ++i)
#pragma unroll
      for (int j = 0; j < 4; ++j)
        acc[i][j] = __builtin_amdgcn_mfma_f32_16x16x32_bf16(a[i], b[j], acc[i][j], 0, 0, 0);
  }

  float bj[4];
#pragma unroll
  for (int j = 0; j < 4; ++j)
    bj[j] = bias[n0 + wn * 64 + j * 16 + t];

  if (blockIdx.z == 2) {
#pragma unroll
    for (int i = 0; i < 4; ++i)
#pragma unroll
      for (int j = 0; j < 4; ++j) {
        int m = m0 + wm * 64 + i * 16 + quad * 4;
        int n = n0 + wn * 64 + j * 16 + t;
        int bb = m >> 11, kv = m & 2047;
        int hh = n >> 6,  dv = n & 63;
        uint2v o;
        o.x = pack2(acc[i][j][0] + bj[j], acc[i][j][1] + bj[j]);
        o.y = pack2(acc[i][j][2] + bj[j], acc[i][j][3] + bj[j]);
        *(uint2v*)&VT[(size_t)(((bb * 16 + hh) * 64) + dv) * 2048 + kv] = o;
      }
  } else {
    const bool isq = (blockIdx.z == 0);
    __hip_bfloat16* Out = isq ? Q : Kk;
    const float sc = isq ? SCALE2 : 1.0f;
#pragma unroll
    for (int i = 0; i < 4; ++i)
#pragma unroll
      for (int j = 0; j < 4; ++j)
#pragma unroll
        for (int r = 0; r < 4; ++r) {
          int m = m0 + wm * 64 + i * 16 + quad * 4 + r;
          int n = n0 + wn * 64 + j * 16 + t;
          Out[(size_t)m * N + n] = __float2bfloat16((acc[i][j][r] + bj[j]) * sc);
        }
  }
}

// ---------------- Output projection ----------------
__global__ __launch_bounds__(256) void proj_gemm_kernel(
    const __hip_bfloat16* __restrict__ X, const __hip_bfloat16* __restrict__ W,
    const float* __restrict__ bias, float* __restrict__ Out)
{
  constexpr int K = 1024, N = 1024;
  __shared__ alignas(16) __hip_bfloat16 As[128 * 32];
  __shared__ alignas(16) __hip_bfloat16 Bs[128 * 32];
  const int tid  = threadIdx.x;
  const int lane = tid & 63;
  const int wave = tid >> 6;
  const int t    = lane & 15;
  const int quad = lane >> 4;
  const int wm   = wave >> 1;
  const int wn   = wave & 1;
  int m0, n0;
  swz(blockIdx.x, m0, n0);

  f32x4 acc[4][4] = {};

  for (int k0 = 0; k0 < K; k0 += 32) {
    __syncthreads();
#pragma unroll
    for (int r = 0; r < 2; ++r) {
      int c   = r * 256 + tid;
      int row = c >> 2;
      int col = (c & 3) * 8;
      async_copy16(&X[(size_t)(m0 + row) * K + k0 + col], &As[c * 8]);
      async_copy16(&W[(size_t)(n0 + row) * K + k0 + col], &Bs[c * 8]);
    }
    __syncthreads();
    bf16x8 a[4], b[4];
#pragma unroll
    for (int i = 0; i < 4; ++i)
      a[i] = *(const bf16x8*)&As[(wm * 64 + i * 16 + t) * 32 + quad * 8];
#pragma unroll
    for (int j = 0; j < 4; ++j)
      b[j] = *(const bf16x8*)&Bs[(wn * 64 + j * 16 + t) * 32 + quad * 8];
#pragma unroll
    for (int i = 0; i < 4; ++i)
#pragma unroll
      for (int j = 0; j < 4; ++j)
        acc[i][j] = __builtin_amdgcn_mfma_f32_16x16x32_bf16(a[i], b[j], acc[i][j], 0, 0, 0);
  }

  float bj[4];
#pragma unroll
  for (int j = 0; j < 4; ++j)
    bj[j] = bias[n0 + wn * 64 + j * 16 + t];
#pragma unroll
  for (int i = 0; i < 4; ++i)
#pragma unroll
    for (int j = 0; j < 4; ++j)
#pragma unroll
      for (int r = 0; r < 4; ++r) {
        int m = m0 + wm * 64 + i * 16 + quad * 4 + r;
        int n = n0 + wn * 64 + j * 16 + t;
        Out[(size_t)m * N + n] = acc[i][j][r] + bj[j];
      }
}

// ---------------- Flash attention: no-max exp2 softmax, 128-kv tiles ----------------
// Round-7 LDS layout (plain strides, measured-best conflicts); kv-tile doubled
// to 128 to halve barrier count (16 tile-iterations).
__global__ __launch_bounds__(256) void attn_kernel(
    const __hip_bfloat16* __restrict__ Qb,
    const __hip_bfloat16* __restrict__ Kb,
    const __hip_bfloat16* __restrict__ VT,
    const unsigned long long* __restrict__ mbits,
    __hip_bfloat16* __restrict__ Ob)
{
  const int bid = blockIdx.x;
  const int qt = bid & 31;
  const int h  = (bid >> 5) & 15;
  const int b  = bid >> 9;
  const int qb = qt * 64;

  __shared__ alignas(16) __hip_bfloat16 Qs[64 * QK_STR];    // 10240 B
  __shared__ alignas(16) __hip_bfloat16 Ks[128 * QK_STR];   // 20480 B
  __shared__ alignas(16) __hip_bfloat16 Vt[64 * VT_STR];    // 17408 B  Vt[dv][kv 0..127]

  const int tid  = threadIdx.x;
  const int lane = tid & 63;
  const int wave = tid >> 6;
  const int t    = lane & 15;
  const int quad = lane >> 4;

  // stage Q tile [64 q][64 d]
#pragma unroll
  for (int r = 0; r < 2; ++r) {
    int c = r * 256 + tid;
    int row = c >> 3, d0 = (c & 7) * 8;
    uint4 raw = *(const uint4*)&Qb[((size_t)(b * S_LEN + qb + row)) * DIM_ + h * HDIM + d0];
    *(uint4*)&Qs[row * QK_STR + d0] = raw;
  }
  __syncthreads();

  bf16x8 qf[2];
#pragma unroll
  for (int ks = 0; ks < 2; ++ks)
    qf[ks] = *(const bf16x8*)&Qs[(wave * 16 + t) * QK_STR + ks * 32 + quad * 8];

  float lp = 0.f;        // lane-local partial softmax denominator (q = t)
  f32x4 o[4] = {};       // O^T[dv = n*16+quad*4+r][q = t]

  const int qg = qb + wave * 16 + t;
  const size_t vtbase = (size_t)((b * 16 + h) * 64) * 2048;
  const size_t mbase = ((size_t)b * S_LEN + qg) * 32;

  for (int kvt = 0; kvt < 16; ++kvt) {
    const int kvb = kvt * 128;
    unsigned long long mw0 = mbits[mbase + kvt * 2];
    unsigned long long mw1 = mbits[mbase + kvt * 2 + 1];
    __syncthreads();
    // K: 128 rows x 64 d  (4 uint4 chunks/thread)
#pragma unroll
    for (int r = 0; r < 4; ++r) {
      int c = r * 256 + tid;
      int row = c >> 3, d0 = (c & 7) * 8;
      uint4 kraw = *(const uint4*)&Kb[((size_t)(b * S_LEN + kvb + row)) * DIM_ + h * HDIM + d0];
      *(uint4*)&Ks[row * QK_STR + d0] = kraw;
    }
    // V^T: 64 dv rows x 128 kv  (4 uint4 chunks/thread)
#pragma unroll
    for (int r = 0; r < 4; ++r) {
      int c = r * 256 + tid;
      int row = c >> 4, cg = (c & 15) * 8;
      uint4 vraw = *(const uint4*)&VT[vtbase + (size_t)row * 2048 + kvb + cg];
      *(uint4*)&Vt[row * VT_STR + cg] = vraw;
    }
    __syncthreads();

    // St[kv][q] = K·(Q*SCALE2)^T ; 8 kv sub-tiles of 16
    float e[8][4];
#pragma unroll
    for (int i = 0; i < 8; ++i) {
      f32x4 z = {};
      bf16x8 a0 = *(const bf16x8*)&Ks[(i * 16 + t) * QK_STR + quad * 8];
      z = __builtin_amdgcn_mfma_f32_16x16x32_bf16(a0, qf[0], z, 0, 0, 0);
      bf16x8 a1 = *(const bf16x8*)&Ks[(i * 16 + t) * QK_STR + 32 + quad * 8];
      z = __builtin_amdgcn_mfma_f32_16x16x32_bf16(a1, qf[1], z, 0, 0, 0);
      unsigned long long mw = (i < 4) ? mw0 : mw1;
      unsigned mq = (unsigned)((mw >> ((i & 3) * 16 + quad * 4)) & 0xFull);
#pragma unroll
      for (int r = 0; r < 4; ++r) {
        float v = ((mq >> r) & 1u) ? -1e20f : z[r];
        float ex = EXP2F(v);
        e[i][r] = ex;
        lp += ex;
      }
    }

    // pack P^T sub-tiles (B-frag of 16x16x16: k=quad*4+i, n=t == St C-layout)
    short4v pf[8];
#pragma unroll
    for (int j = 0; j < 8; ++j) {
      uint2v pk;
      pk.x = pack2f(e[j][0], e[j][1]);
      pk.y = pack2f(e[j][2], e[j][3]);
      pf[j] = __builtin_bit_cast(short4v, pk);
    }

    // O^T += V^T · P^T  (A[m=t][k=quad*4+i] from Vt rows)
#pragma unroll
    for (int j = 0; j < 8; ++j)
#pragma unroll
      for (int n = 0; n < 4; ++n) {
        short4v va = *(const short4v*)&Vt[(n * 16 + t) * VT_STR + j * 16 + quad * 4];
        o[n] = __builtin_amdgcn_mfma_f32_16x16x16bf16_1k(va, pf[j], o[n], 0, 0, 0);
      }
  }

  // reduce denominator across quads (kv split), normalize
  lp += __shfl_xor(lp, 16, 64);
  lp += __shfl_xor(lp, 32, 64);
  float rl = 1.0f / lp;

  // transpose O^T -> O via Qs, coalesced store
  __hip_bfloat16* Ts = Qs;
  __syncthreads();
#pragma unroll
  for (int n = 0; n < 4; ++n) {
    uint2v pk;
    pk.x = pack2f(o[n][0] * rl, o[n][1] * rl);
    pk.y = pack2f(o[n][2] * rl, o[n][3] * rl);
    *(uint2v*)&Ts[(wave * 16 + t) * QK_STR + n * 16 + quad * 4] = pk;
  }
  __syncthreads();
  {
    int row = tid >> 2;          // q local
    int d0  = (tid & 3) * 16;    // dv base
    uint4 x0 = *(const uint4*)&Ts[row * QK_STR + d0];
    uint4 x1 = *(const uint4*)&Ts[row * QK_STR + d0 + 8];
    __hip_bfloat16* dst = &Ob[((size_t)(b * S_LEN + qb + row)) * DIM_ + h * HDIM + d0];
    *(uint4*)dst = x0;
    *(uint4*)(dst + 8) = x1;
  }
}

extern "C" void kernel_launch(void* const* d_in, const int* in_sizes, int n_in,
                              void* d_out, int out_size, void* d_ws, size_t ws_size,
                              hipStream_t stream) {
  const float* q  = (const float*)d_in[0];
  const float* k  = (const float*)d_in[1];
  const float* v  = (const float*)d_in[2];
  const int*   mk = (const int*)d_in[3];
  const float* Wq = (const float*)d_in[4];
  const float* bq = (const float*)d_in[5];
  const float* Wk = (const float*)d_in[6];
  const float* bk = (const float*)d_in[7];
  const float* Wv = (const float*)d_in[8];
  const float* bv = (const float*)d_in[9];
  const float* Wo = (const float*)d_in[10];
  const float* bo = (const float*)d_in[11];
  float* out = (float*)d_out;

  char* ws = (char*)d_ws;
  const size_t MB = 1024 * 1024;
  __hip_bfloat16* Qb  = (__hip_bfloat16*)(ws);
  __hip_bfloat16* Kb  = (__hip_bfloat16*)(ws + 8  * MB);
  __hip_bfloat16* VTb = (__hip_bfloat16*)(ws + 16 * MB);
  __hip_bfloat16* Ob  = (__hip_bfloat16*)(ws + 24 * MB);
  __hip_bfloat16* xqb = (__hip_bfloat16*)(ws + 32 * MB);
  __hip_bfloat16* xkb = (__hip_bfloat16*)(ws + 40 * MB);
  __hip_bfloat16* xvb = (__hip_bfloat16*)(ws + 48 * MB);
  __hip_bfloat16* Wqb = (__hip_bfloat16*)(ws + 56 * MB);
  __hip_bfloat16* Wkb = (__hip_bfloat16*)(ws + 58 * MB);
  __hip_bfloat16* Wvb = (__hip_bfloat16*)(ws + 60 * MB);
  __hip_bfloat16* Wob = (__hip_bfloat16*)(ws + 62 * MB);
  unsigned long long* mbits = (unsigned long long*)(ws + 64 * MB);

  cvt_kernel<<<dim3(2048, 7), 256, 0, stream>>>(q, k, v, Wq, Wk, Wv, Wo,
                                                xqb, xkb, xvb, Wqb, Wkb, Wvb, Wob);
  maskbits_kernel<<<dim3(32768), 256, 0, stream>>>(mk, mbits);
  qkv_gemm_kernel<<<dim3(256, 1, 3), 256, 0, stream>>>(xqb, xkb, xvb,
                                                       Wqb, bq, Wkb, bk, Wvb, bv,
                                                       Qb, Kb, VTb);
  attn_kernel<<<dim3(1024), 256, 0, stream>>>(Qb, Kb, VTb, mbits, Ob);
  proj_gemm_kernel<<<dim3(256), 256, 0, stream>>>(Ob, Wob, bo, out);
}

// Round 10
// 291.890 us; speedup vs baseline: 1.2223x; 1.2223x over previous
//
#include <hip/hip_runtime.h>
#include <hip/hip_bf16.h>

typedef __attribute__((ext_vector_type(8))) __bf16 bf16x8;
typedef __attribute__((ext_vector_type(4))) short short4v;
typedef __attribute__((ext_vector_type(4))) float f32x4;
typedef __attribute__((ext_vector_type(4))) unsigned int uint4v;
typedef __attribute__((ext_vector_type(2))) unsigned int uint2v;

#define S_LEN 2048
#define DIM_  1024
#define HDIM  64
// SCALE * log2(e), folded into Q at projection time
#define SCALE2 0.045084441f
#define QK_STR 80   // Qs/Ks row stride (160 B) — R7 measured-best
#define V_STR  72   // Vt row stride (144 B) — R7 measured-best

#define EXP2F(x) __builtin_amdgcn_exp2f(x)

__device__ __forceinline__ void async_copy16(const void* gp, void* lp) {
  __builtin_amdgcn_global_load_lds(
      (const __attribute__((address_space(1))) unsigned int*)gp,
      (__attribute__((address_space(3))) unsigned int*)lp, 16, 0, 0);
}

__device__ __forceinline__ unsigned f2bf_u(float f) {
  unsigned u = __builtin_bit_cast(unsigned, f);
  return (u + 0x7FFFu + ((u >> 16) & 1u)) >> 16;
}
__device__ __forceinline__ unsigned pack2(float a, float b) {
  return f2bf_u(a) | (f2bf_u(b) << 16);
}
// round-half-up bf16 pair pack: 2 adds + 1 v_perm
__device__ __forceinline__ unsigned pack2f(float a, float b) {
  unsigned ua = __builtin_bit_cast(unsigned, a) + 0x8000u;
  unsigned ub = __builtin_bit_cast(unsigned, b) + 0x8000u;
  return __builtin_amdgcn_perm(ub, ua, 0x07060302u);
}

// ---------------- input f32 -> bf16 conversion ----------------
__global__ __launch_bounds__(256) void cvt_kernel(
    const float* __restrict__ s0, const float* __restrict__ s1, const float* __restrict__ s2,
    const float* __restrict__ s3, const float* __restrict__ s4, const float* __restrict__ s5,
    const float* __restrict__ s6,
    __hip_bfloat16* __restrict__ d0, __hip_bfloat16* __restrict__ d1, __hip_bfloat16* __restrict__ d2,
    __hip_bfloat16* __restrict__ d3, __hip_bfloat16* __restrict__ d4, __hip_bfloat16* __restrict__ d5,
    __hip_bfloat16* __restrict__ d6)
{
  const float* srcs[7] = {s0, s1, s2, s3, s4, s5, s6};
  __hip_bfloat16* dsts[7] = {d0, d1, d2, d3, d4, d5, d6};
  const int sizes[7] = {4194304, 4194304, 4194304, 1048576, 1048576, 1048576, 1048576};
  int rg = blockIdx.y;
  int base = (blockIdx.x * 256 + threadIdx.x) * 8;
  if (base >= sizes[rg]) return;
  const float* s = srcs[rg] + base;
  f32x4 a = *(const f32x4*)s;
  f32x4 b = *(const f32x4*)(s + 4);
  uint4v o;
  o.x = pack2(a[0], a[1]); o.y = pack2(a[2], a[3]);
  o.z = pack2(b[0], b[1]); o.w = pack2(b[2], b[3]);
  *(uint4v*)(dsts[rg] + base) = o;
}

// ---------------- mask int32 -> 64-bit words via ballot ----------------
__global__ __launch_bounds__(256) void maskbits_kernel(
    const int* __restrict__ mask, unsigned long long* __restrict__ bits)
{
  int w = (blockIdx.x * 256 + threadIdx.x) >> 6;
  int lane = threadIdx.x & 63;
  int m = mask[(size_t)w * 64 + lane];
  unsigned long long bal = __ballot(m != 0);
  if (lane == 0) bits[w] = bal;
}

// L2 swizzle: 8 consecutive blocks share one n-tile, sweep m
__device__ __forceinline__ void swz(int r, int& m0, int& n0) {
  int g  = r >> 6;
  int yy = (r >> 3) & 7;
  int xl = r & 7;
  m0 = (g * 8 + xl) * 128;
  n0 = yy * 128;
}

// ---------------- QKV projection (bf16, double-buffered async staging) ----------------
__global__ __launch_bounds__(256) void qkv_gemm_kernel(
    const __hip_bfloat16* __restrict__ xq, const __hip_bfloat16* __restrict__ xk,
    const __hip_bfloat16* __restrict__ xv,
    const __hip_bfloat16* __restrict__ Wq, const float* __restrict__ bq,
    const __hip_bfloat16* __restrict__ Wk, const float* __restrict__ bk,
    const __hip_bfloat16* __restrict__ Wv, const float* __restrict__ bv,
    __hip_bfloat16* __restrict__ Q, __hip_bfloat16* __restrict__ Kk,
    __hip_bfloat16* __restrict__ VT)
{
  const __hip_bfloat16 *X, *W; const float* bias;
  if (blockIdx.z == 0)      { X = xq; W = Wq; bias = bq; }
  else if (blockIdx.z == 1) { X = xk; W = Wk; bias = bk; }
  else                      { X = xv; W = Wv; bias = bv; }

  constexpr int K = 1024, N = 1024;
  __shared__ alignas(16) __hip_bfloat16 As[2][128 * 32];
  __shared__ alignas(16) __hip_bfloat16 Bs[2][128 * 32];
  const int tid  = threadIdx.x;
  const int lane = tid & 63;
  const int wave = tid >> 6;
  const int t    = lane & 15;
  const int quad = lane >> 4;
  const int wm   = wave >> 1;
  const int wn   = wave & 1;
  int m0, n0;
  swz(blockIdx.x, m0, n0);

  f32x4 acc[4][4] = {};

  // per-thread staging addresses
  const int c0 = tid, c1 = 256 + tid;
  const int r0 = c0 >> 2, o0 = (c0 & 3) * 8;
  const int r1 = c1 >> 2, o1 = (c1 & 3) * 8;
  const __hip_bfloat16* xp0 = &X[(size_t)(m0 + r0) * K + o0];
  const __hip_bfloat16* xp1 = &X[(size_t)(m0 + r1) * K + o1];
  const __hip_bfloat16* wp0 = &W[(size_t)(n0 + r0) * K + o0];
  const __hip_bfloat16* wp1 = &W[(size_t)(n0 + r1) * K + o1];

  // prologue: stage k0=0 into buf 0
  async_copy16(xp0, &As[0][c0 * 8]);
  async_copy16(xp1, &As[0][c1 * 8]);
  async_copy16(wp0, &Bs[0][c0 * 8]);
  async_copy16(wp1, &Bs[0][c1 * 8]);

  int buf = 0;
  for (int k0 = 0; k0 < K; k0 += 32) {
    __syncthreads();   // drains staging of `buf`
    if (k0 + 32 < K) {
      int nb = buf ^ 1;
      int kn = k0 + 32;
      async_copy16(xp0 + kn, &As[nb][c0 * 8]);
      async_copy16(xp1 + kn, &As[nb][c1 * 8]);
      async_copy16(wp0 + kn, &Bs[nb][c0 * 8]);
      async_copy16(wp1 + kn, &Bs[nb][c1 * 8]);
    }
    bf16x8 a[4], b[4];
#pragma unroll
    for (int i = 0; i < 4; ++i)
      a[i] = *(const bf16x8*)&As[buf][(wm * 64 + i * 16 + t) * 32 + quad * 8];
#pragma unroll
    for (int j = 0; j < 4; ++j)
      b[j] = *(const bf16x8*)&Bs[buf][(wn * 64 + j * 16 + t) * 32 + quad * 8];
#pragma unroll
    for (int i = 0; i < 4; ++i)
#pragma unroll
      for (int j = 0; j < 4; ++j)
        acc[i][j] = __builtin_amdgcn_mfma_f32_16x16x32_bf16(a[i], b[j], acc[i][j], 0, 0, 0);
    buf ^= 1;
  }

  float bj[4];
#pragma unroll
  for (int j = 0; j < 4; ++j)
    bj[j] = bias[n0 + wn * 64 + j * 16 + t];

  if (blockIdx.z == 2) {
#pragma unroll
    for (int i = 0; i < 4; ++i)
#pragma unroll
      for (int j = 0; j < 4; ++j) {
        int m = m0 + wm * 64 + i * 16 + quad * 4;
        int n = n0 + wn * 64 + j * 16 + t;
        int bb = m >> 11, kv = m & 2047;
        int hh = n >> 6,  dv = n & 63;
        uint2v o;
        o.x = pack2(acc[i][j][0] + bj[j], acc[i][j][1] + bj[j]);
        o.y = pack2(acc[i][j][2] + bj[j], acc[i][j][3] + bj[j]);
        *(uint2v*)&VT[(size_t)(((bb * 16 + hh) * 64) + dv) * 2048 + kv] = o;
      }
  } else {
    const bool isq = (blockIdx.z == 0);
    __hip_bfloat16* Out = isq ? Q : Kk;
    const float sc = isq ? SCALE2 : 1.0f;
#pragma unroll
    for (int i = 0; i < 4; ++i)
#pragma unroll
      for (int j = 0; j < 4; ++j)
#pragma unroll
        for (int r = 0; r < 4; ++r) {
          int m = m0 + wm * 64 + i * 16 + quad * 4 + r;
          int n = n0 + wn * 64 + j * 16 + t;
          Out[(size_t)m * N + n] = __float2bfloat16((acc[i][j][r] + bj[j]) * sc);
        }
  }
}

// ---------------- Output projection (double-buffered) ----------------
__global__ __launch_bounds__(256) void proj_gemm_kernel(
    const __hip_bfloat16* __restrict__ X, const __hip_bfloat16* __restrict__ W,
    const float* __restrict__ bias, float* __restrict__ Out)
{
  constexpr int K = 1024, N = 1024;
  __shared__ alignas(16) __hip_bfloat16 As[2][128 * 32];
  __shared__ alignas(16) __hip_bfloat16 Bs[2][128 * 32];
  const int tid  = threadIdx.x;
  const int lane = tid & 63;
  const int wave = tid >> 6;
  const int t    = lane & 15;
  const int quad = lane >> 4;
  const int wm   = wave >> 1;
  const int wn   = wave & 1;
  int m0, n0;
  swz(blockIdx.x, m0, n0);

  f32x4 acc[4][4] = {};

  const int c0 = tid, c1 = 256 + tid;
  const int r0 = c0 >> 2, o0 = (c0 & 3) * 8;
  const int r1 = c1 >> 2, o1 = (c1 & 3) * 8;
  const __hip_bfloat16* xp0 = &X[(size_t)(m0 + r0) * K + o0];
  const __hip_bfloat16* xp1 = &X[(size_t)(m0 + r1) * K + o1];
  const __hip_bfloat16* wp0 = &W[(size_t)(n0 + r0) * K + o0];
  const __hip_bfloat16* wp1 = &W[(size_t)(n0 + r1) * K + o1];

  async_copy16(xp0, &As[0][c0 * 8]);
  async_copy16(xp1, &As[0][c1 * 8]);
  async_copy16(wp0, &Bs[0][c0 * 8]);
  async_copy16(wp1, &Bs[0][c1 * 8]);

  int buf = 0;
  for (int k0 = 0; k0 < K; k0 += 32) {
    __syncthreads();
    if (k0 + 32 < K) {
      int nb = buf ^ 1;
      int kn = k0 + 32;
      async_copy16(xp0 + kn, &As[nb][c0 * 8]);
      async_copy16(xp1 + kn, &As[nb][c1 * 8]);
      async_copy16(wp0 + kn, &Bs[nb][c0 * 8]);
      async_copy16(wp1 + kn, &Bs[nb][c1 * 8]);
    }
    bf16x8 a[4], b[4];
#pragma unroll
    for (int i = 0; i < 4; ++i)
      a[i] = *(const bf16x8*)&As[buf][(wm * 64 + i * 16 + t) * 32 + quad * 8];
#pragma unroll
    for (int j = 0; j < 4; ++j)
      b[j] = *(const bf16x8*)&Bs[buf][(wn * 64 + j * 16 + t) * 32 + quad * 8];
#pragma unroll
    for (int i = 0; i < 4; ++i)
#pragma unroll
      for (int j = 0; j < 4; ++j)
        acc[i][j] = __builtin_amdgcn_mfma_f32_16x16x32_bf16(a[i], b[j], acc[i][j], 0, 0, 0);
    buf ^= 1;
  }

  float bj[4];
#pragma unroll
  for (int j = 0; j < 4; ++j)
    bj[j] = bias[n0 + wn * 64 + j * 16 + t];
#pragma unroll
  for (int i = 0; i < 4; ++i)
#pragma unroll
    for (int j = 0; j < 4; ++j)
#pragma unroll
      for (int r = 0; r < 4; ++r) {
        int m = m0 + wm * 64 + i * 16 + quad * 4 + r;
        int n = n0 + wn * 64 + j * 16 + t;
        Out[(size_t)m * N + n] = acc[i][j][r] + bj[j];
      }
}

// ---------------- Flash attention: R7 structure + no-max exp2 softmax ----------------
__global__ __launch_bounds__(256) void attn_kernel(
    const __hip_bfloat16* __restrict__ Qb,
    const __hip_bfloat16* __restrict__ Kb,
    const __hip_bfloat16* __restrict__ VT,
    const unsigned long long* __restrict__ mbits,
    __hip_bfloat16* __restrict__ Ob)
{
  const int bid = blockIdx.x;
  const int qt = bid & 31;
  const int h  = (bid >> 5) & 15;
  const int b  = bid >> 9;
  const int qb = qt * 64;

  __shared__ alignas(16) __hip_bfloat16 Qs[64 * QK_STR];
  __shared__ alignas(16) __hip_bfloat16 Ks[64 * QK_STR];
  __shared__ alignas(16) __hip_bfloat16 Vt[64 * V_STR];   // Vt[dv][kv]

  const int tid  = threadIdx.x;
  const int lane = tid & 63;
  const int wave = tid >> 6;
  const int t    = lane & 15;
  const int quad = lane >> 4;

#pragma unroll
  for (int r = 0; r < 2; ++r) {
    int c = r * 256 + tid;
    int row = c >> 3, d0 = (c & 7) * 8;
    uint4 raw = *(const uint4*)&Qb[((size_t)(b * S_LEN + qb + row)) * DIM_ + h * HDIM + d0];
    *(uint4*)&Qs[row * QK_STR + d0] = raw;
  }
  __syncthreads();

  bf16x8 qf[2];
#pragma unroll
  for (int ks = 0; ks < 2; ++ks)
    qf[ks] = *(const bf16x8*)&Qs[(wave * 16 + t) * QK_STR + ks * 32 + quad * 8];

  float lp = 0.f;        // lane-local partial softmax denominator (q = t)
  f32x4 o[4] = {};       // O^T[dv = n*16+quad*4+r][q = t]

  const int qg = qb + wave * 16 + t;
  const size_t vtbase = (size_t)((b * 16 + h) * 64) * 2048;
  const size_t mbase = ((size_t)b * S_LEN + qg) * 32;

  for (int kvt = 0; kvt < 32; ++kvt) {
    const int kvb = kvt * 64;
    unsigned long long mw = mbits[mbase + kvt];
    __syncthreads();
#pragma unroll
    for (int r = 0; r < 2; ++r) {
      int c = r * 256 + tid;
      int row = c >> 3, d0 = (c & 7) * 8;
      uint4 kraw = *(const uint4*)&Kb[((size_t)(b * S_LEN + kvb + row)) * DIM_ + h * HDIM + d0];
      *(uint4*)&Ks[row * QK_STR + d0] = kraw;
      uint4 vraw = *(const uint4*)&VT[vtbase + (size_t)row * 2048 + kvb + d0];
      *(uint4*)&Vt[row * V_STR + d0] = vraw;
    }
    __syncthreads();

    // St[kv][q] = K·(Q*SCALE2)^T ; p = exp2(masked); lane-local denominator
    float e[4][4];
#pragma unroll
    for (int i = 0; i < 4; ++i) {
      f32x4 z = {};
      bf16x8 a0 = *(const bf16x8*)&Ks[(i * 16 + t) * QK_STR + quad * 8];
      z = __builtin_amdgcn_mfma_f32_16x16x32_bf16(a0, qf[0], z, 0, 0, 0);
      bf16x8 a1 = *(const bf16x8*)&Ks[(i * 16 + t) * QK_STR + 32 + quad * 8];
      z = __builtin_amdgcn_mfma_f32_16x16x32_bf16(a1, qf[1], z, 0, 0, 0);
      unsigned mq = (unsigned)((mw >> (i * 16 + quad * 4)) & 0xFull);
#pragma unroll
      for (int r = 0; r < 4; ++r) {
        float v = ((mq >> r) & 1u) ? -1e20f : z[r];
        float ex = EXP2F(v);
        e[i][r] = ex;
        lp += ex;
      }
    }

    // pack P^T sub-tiles (B-frag of 16x16x16: k=quad*4+i, n=t == St C-layout)
    short4v pf[4];
#pragma unroll
    for (int j = 0; j < 4; ++j) {
      uint2v pk;
      pk.x = pack2f(e[j][0], e[j][1]);
      pk.y = pack2f(e[j][2], e[j][3]);
      pf[j] = __builtin_bit_cast(short4v, pk);
    }

    // O^T += V^T · P^T  (A[m=t][k=quad*4+i] from Vt rows)
#pragma unroll
    for (int j = 0; j < 4; ++j)
#pragma unroll
      for (int n = 0; n < 4; ++n) {
        short4v va = *(const short4v*)&Vt[(n * 16 + t) * V_STR + j * 16 + quad * 4];
        o[n] = __builtin_amdgcn_mfma_f32_16x16x16bf16_1k(va, pf[j], o[n], 0, 0, 0);
      }
  }

  // reduce denominator across quads (kv split), normalize
  lp += __shfl_xor(lp, 16, 64);
  lp += __shfl_xor(lp, 32, 64);
  float rl = 1.0f / lp;

  // transpose O^T -> O via Qs, coalesced store
  __hip_bfloat16* Ts = Qs;
  __syncthreads();
#pragma unroll
  for (int n = 0; n < 4; ++n) {
    uint2v pk;
    pk.x = pack2f(o[n][0] * rl, o[n][1] * rl);
    pk.y = pack2f(o[n][2] * rl, o[n][3] * rl);
    *(uint2v*)&Ts[(wave * 16 + t) * V_STR + n * 16 + quad * 4] = pk;
  }
  __syncthreads();
  {
    int row = tid >> 2;          // q local
    int d0  = (tid & 3) * 16;    // dv base
    uint4 x0 = *(const uint4*)&Ts[row * V_STR + d0];
    uint4 x1 = *(const uint4*)&Ts[row * V_STR + d0 + 8];
    __hip_bfloat16* dst = &Ob[((size_t)(b * S_LEN + qb + row)) * DIM_ + h * HDIM + d0];
    *(uint4*)dst = x0;
    *(uint4*)(dst + 8) = x1;
  }
}

extern "C" void kernel_launch(void* const* d_in, const int* in_sizes, int n_in,
                              void* d_out, int out_size, void* d_ws, size_t ws_size,
                              hipStream_t stream) {
  const float* q  = (const float*)d_in[0];
  const float* k  = (const float*)d_in[1];
  const float* v  = (const float*)d_in[2];
  const int*   mk = (const int*)d_in[3];
  const float* Wq = (const float*)d_in[4];
  const float* bq = (const float*)d_in[5];
  const float* Wk = (const float*)d_in[6];
  const float* bk = (const float*)d_in[7];
  const float* Wv = (const float*)d_in[8];
  const float* bv = (const float*)d_in[9];
  const float* Wo = (const float*)d_in[10];
  const float* bo = (const float*)d_in[11];
  float* out = (float*)d_out;

  char* ws = (char*)d_ws;
  const size_t MB = 1024 * 1024;
  __hip_bfloat16* Qb  = (__hip_bfloat16*)(ws);
  __hip_bfloat16* Kb  = (__hip_bfloat16*)(ws + 8  * MB);
  __hip_bfloat16* VTb = (__hip_bfloat16*)(ws + 16 * MB);
  __hip_bfloat16* Ob  = (__hip_bfloat16*)(ws + 24 * MB);
  __hip_bfloat16* xqb = (__hip_bfloat16*)(ws + 32 * MB);
  __hip_bfloat16* xkb = (__hip_bfloat16*)(ws + 40 * MB);
  __hip_bfloat16* xvb = (__hip_bfloat16*)(ws + 48 * MB);
  __hip_bfloat16* Wqb = (__hip_bfloat16*)(ws + 56 * MB);
  __hip_bfloat16* Wkb = (__hip_bfloat16*)(ws + 58 * MB);
  __hip_bfloat16* Wvb = (__hip_bfloat16*)(ws + 60 * MB);
  __hip_bfloat16* Wob = (__hip_bfloat16*)(ws + 62 * MB);
  unsigned long long* mbits = (unsigned long long*)(ws + 64 * MB);

  cvt_kernel<<<dim3(2048, 7), 256, 0, stream>>>(q, k, v, Wq, Wk, Wv, Wo,
                                                xqb, xkb, xvb, Wqb, Wkb, Wvb, Wob);
  maskbits_kernel<<<dim3(32768), 256, 0, stream>>>(mk, mbits);
  qkv_gemm_kernel<<<dim3(256, 1, 3), 256, 0, stream>>>(xqb, xkb, xvb,
                                                       Wqb, bq, Wkb, bk, Wvb, bv,
                                                       Qb, Kb, VTb);
  attn_kernel<<<dim3(1024), 256, 0, stream>>>(Qb, Kb, VTb, mbits, Ob);
  proj_gemm_kernel<<<dim3(256), 256, 0, stream>>>(Ob, Wob, bo, out);
}